// Round 2
// baseline (2136.993 us; speedup 1.0000x reference)
//
#include <hip/hip_runtime.h>
#include <math.h>

#define SS 2048
#define BB 64
#define XDIM 64
#define DXF 128
#define HH 256
#define DHH 128

typedef float v2f __attribute__((ext_vector_type(2)));

// tanh(x) = 1 - 2/(exp(2x)+1); __expf -> v_exp_f32, ~1e-6 abs err, saturates correctly.
__device__ __forceinline__ float ftanh(float x) {
    float e = __expf(2.0f * x);
    return 1.0f - 2.0f / (e + 1.0f);
}

template <int CTRL>
__device__ __forceinline__ float dpp_mov_f(float x) {
    return __int_as_float(__builtin_amdgcn_update_dpp(
        0, __float_as_int(x), CTRL, 0xF, 0xF, true));
}

// ---------------------------------------------------------------------------
// K1: u[e,i] = bih[i]+bhh[i] + sum_j tanh(bx[j] + sum_m x[e,m]Wx[m,j]) * Wih[i,j]
// 64 rows/block, 256 threads. Register tiles: 4 cols x 4 rows, float4 LDS reads.
// ---------------------------------------------------------------------------
__global__ __launch_bounds__(256) void k1_featu(
    const float* __restrict__ x, const float* __restrict__ Wx,
    const float* __restrict__ bx, const float* __restrict__ Wih,
    const float* __restrict__ bih, const float* __restrict__ bhh,
    float* __restrict__ u)
{
    __shared__ float xs[64][XDIM];   // 16KB
    __shared__ float fs[64][DXF];    // 32KB
    const int tid = threadIdx.x;
    const size_t row0 = (size_t)blockIdx.x * 64;

    for (int v = tid; v < 64 * XDIM; v += 256) {
        int r = v >> 6, m = v & 63;
        xs[r][m] = x[(row0 + r) * XDIM + m];
    }
    __syncthreads();

    // stage 2: fs = tanh(xs @ Wx + bx). cols: cq+32j; rows: 8ru..8ru+7
    {
        const int cq = tid & 31;
        const int ru = tid >> 5;
        v2f aA[2][4], aB[2][4];
        #pragma unroll
        for (int g = 0; g < 2; ++g)
            #pragma unroll
            for (int i = 0; i < 4; ++i) { aA[g][i] = (v2f)0.f; aB[g][i] = (v2f)0.f; }

        #pragma unroll
        for (int kc = 0; kc < 4; ++kc) {          // K=64, KC=16
            v2f wA[16], wB[16];
            #pragma unroll
            for (int k = 0; k < 16; ++k) {
                const float* wp = Wx + (kc * 16 + k) * DXF + cq;
                wA[k] = (v2f){wp[0],  wp[32]};
                wB[k] = (v2f){wp[64], wp[96]};
            }
            #pragma unroll
            for (int g = 0; g < 2; ++g) {
                const int rb = 8 * ru + 4 * g;
                #pragma unroll
                for (int k4 = 0; k4 < 4; ++k4) {
                    float4 xv[4];
                    #pragma unroll
                    for (int i = 0; i < 4; ++i)
                        xv[i] = *(const float4*)&xs[rb + i][kc * 16 + 4 * k4];
                    #pragma unroll
                    for (int i = 0; i < 4; ++i) {
                        #pragma unroll
                        for (int e = 0; e < 4; ++e) {
                            const float xe = (e == 0) ? xv[i].x : (e == 1) ? xv[i].y
                                           : (e == 2) ? xv[i].z : xv[i].w;
                            const v2f xb = (v2f){xe, xe};
                            aA[g][i] += wA[4 * k4 + e] * xb;
                            aB[g][i] += wB[4 * k4 + e] * xb;
                        }
                    }
                }
            }
        }
        const float b0 = bx[cq], b1 = bx[cq + 32], b2 = bx[cq + 64], b3 = bx[cq + 96];
        #pragma unroll
        for (int g = 0; g < 2; ++g)
            #pragma unroll
            for (int i = 0; i < 4; ++i) {
                const int r = 8 * ru + 4 * g + i;
                fs[r][cq]      = ftanh(aA[g][i].x + b0);
                fs[r][cq + 32] = ftanh(aA[g][i].y + b1);
                fs[r][cq + 64] = ftanh(aB[g][i].x + b2);
                fs[r][cq + 96] = ftanh(aB[g][i].y + b3);
            }
    }
    __syncthreads();

    // stage 3: u = fs @ Wih^T + bih + bhh. cols q4+64j; rows 16rq..16rq+15
    {
        const int q4 = tid & 63;
        const int rq = tid >> 6;
        v2f aA[4][4], aB[4][4];
        #pragma unroll
        for (int g = 0; g < 4; ++g)
            #pragma unroll
            for (int i = 0; i < 4; ++i) { aA[g][i] = (v2f)0.f; aB[g][i] = (v2f)0.f; }

        #pragma unroll
        for (int kc = 0; kc < 8; ++kc) {          // K=128, KC=16
            v2f wA[16], wB[16];
            #pragma unroll
            for (int k4 = 0; k4 < 4; ++k4) {
                const float4 w0 = *(const float4*)(Wih + (size_t)(q4      ) * DXF + kc * 16 + 4 * k4);
                const float4 w1 = *(const float4*)(Wih + (size_t)(q4 +  64) * DXF + kc * 16 + 4 * k4);
                const float4 w2 = *(const float4*)(Wih + (size_t)(q4 + 128) * DXF + kc * 16 + 4 * k4);
                const float4 w3 = *(const float4*)(Wih + (size_t)(q4 + 192) * DXF + kc * 16 + 4 * k4);
                wA[4 * k4 + 0] = (v2f){w0.x, w1.x}; wA[4 * k4 + 1] = (v2f){w0.y, w1.y};
                wA[4 * k4 + 2] = (v2f){w0.z, w1.z}; wA[4 * k4 + 3] = (v2f){w0.w, w1.w};
                wB[4 * k4 + 0] = (v2f){w2.x, w3.x}; wB[4 * k4 + 1] = (v2f){w2.y, w3.y};
                wB[4 * k4 + 2] = (v2f){w2.z, w3.z}; wB[4 * k4 + 3] = (v2f){w2.w, w3.w};
            }
            #pragma unroll
            for (int g = 0; g < 4; ++g) {
                const int rb = 16 * rq + 4 * g;
                #pragma unroll
                for (int k4 = 0; k4 < 4; ++k4) {
                    float4 fv[4];
                    #pragma unroll
                    for (int i = 0; i < 4; ++i)
                        fv[i] = *(const float4*)&fs[rb + i][kc * 16 + 4 * k4];
                    #pragma unroll
                    for (int i = 0; i < 4; ++i) {
                        #pragma unroll
                        for (int e = 0; e < 4; ++e) {
                            const float fe = (e == 0) ? fv[i].x : (e == 1) ? fv[i].y
                                           : (e == 2) ? fv[i].z : fv[i].w;
                            const v2f fb = (v2f){fe, fe};
                            aA[g][i] += wA[4 * k4 + e] * fb;
                            aB[g][i] += wB[4 * k4 + e] * fb;
                        }
                    }
                }
            }
        }
        const float b0 = bih[q4]       + bhh[q4];
        const float b1 = bih[q4 + 64]  + bhh[q4 + 64];
        const float b2 = bih[q4 + 128] + bhh[q4 + 128];
        const float b3 = bih[q4 + 192] + bhh[q4 + 192];
        #pragma unroll
        for (int g = 0; g < 4; ++g)
            #pragma unroll
            for (int i = 0; i < 4; ++i) {
                const size_t row = row0 + 16 * rq + 4 * g + i;
                u[row * HH + q4]       = aA[g][i].x + b0;
                u[row * HH + q4 + 64]  = aA[g][i].y + b1;
                u[row * HH + q4 + 128] = aB[g][i].x + b2;
                u[row * HH + q4 + 192] = aB[g][i].y + b3;
            }
    }
}

// ---------------------------------------------------------------------------
// K2: sequential recurrence. One block of 1024 threads per batch element.
//
// R7 RESTRUCTURE. R6 post-mortem: removing the vmcnt(0) barrier drain +
// 4-deep u prefetch changed NOTHING (1516us, VGPR 52, VALU 18% all
// identical) => not latency-bound. VGPR=52 < 64 pinned weight floats =>
// weights live in AGPRs (unified file; VGPR_Count excludes them) =>
// weights were never reloaded. The model that fits ALL counters: the old
// layout (32 k's/thread) issued 8 ds_read_b128 per lane per step =
// 128 b128/CU/step at ~12cy each = ~1536cy vs measured 1776cy/step.
// The LDS pipe was ~87% of the step, reading the 1KB h vector 8x per wave.
//
// New partition: thread (rg=tid>>5, c=tid&31) owns 8 rows x 8 k's
// (rows [8rg,8rg+8), ks [8c,8c+8), still 64 weights/thread).
//   * LDS: 2 ds_read_b128 per lane per step (4x fewer instrs; 32/CU/step).
//     h stored in 48B-strided chunks (chunk c at float offset 12c) so the
//     32 distinct stride-32B reads spread over all 8 bank-quads.
//   * Reduce across the 32 c-lanes with a value-halving butterfly using
//     DPP patterns that exist on gfx950: xor7 = row_half_mirror (0x141),
//     xor1 = quad_perm(1,0,3,2) (0xB1), xor2 = quad_perm(2,3,0,1) (0x4E),
//     xor8 = row_ror:8 (0x128), xor16 = ds_swizzle 0x401F.
//     Halving parities (b2,b0,b1) give row map rl = 4*b2 + 2*b0 + b1
//     (bijection on c&7); stages pair lanes holding the SAME row set.
//   * Owner lanes c<8: add u, tanh, leaky blend, write hbuf[nxt] + hist.
// Budget/step: VALU ~4 waves x (32 pk_fma + 8 add + 32 reduce + ~20 tail)
// x2cy ~ 700cy; LDS ~400cy overlapped; chain ~400cy => ~750-900cy vs 1776.
// ---------------------------------------------------------------------------
__global__ __launch_bounds__(1024)
__attribute__((amdgpu_waves_per_eu(4, 4)))
void k2_rnn(
    const float* __restrict__ u, const float* __restrict__ Whh,
    const float* __restrict__ sigmas, float* __restrict__ hist)
{
    __shared__ float hbuf[2][12 * 32];   // chunk c at [12c..12c+7], 4-float pad
    const int tid = threadIdx.x;
    const int b = blockIdx.x;
    const int c  = tid & 31;             // k-chunk: ks [8c, 8c+8)
    const int rg = tid >> 5;             // row group: rows [8rg, 8rg+8)

    // per-thread weights: w2[r][j] = {Whh[8rg+r][8c+2j], Whh[8rg+r][8c+2j+1]}
    v2f w2[8][4];
    #pragma unroll
    for (int r = 0; r < 8; ++r) {
        const float* wrow = Whh + (size_t)(8 * rg + r) * HH + 8 * c;
        const float4 w0 = *(const float4*)(wrow);
        const float4 w1 = *(const float4*)(wrow + 4);
        w2[r][0] = (v2f){w0.x, w0.y};
        w2[r][1] = (v2f){w0.z, w0.w};
        w2[r][2] = (v2f){w1.x, w1.y};
        w2[r][3] = (v2f){w1.z, w1.w};
    }
    // Pin once: asm results are non-rematerializable.
    #pragma unroll
    for (int r = 0; r < 8; r += 4) {
        asm volatile("" : "+v"(w2[r][0]),     "+v"(w2[r][1]),     "+v"(w2[r][2]),     "+v"(w2[r][3]),
                          "+v"(w2[r + 1][0]), "+v"(w2[r + 1][1]), "+v"(w2[r + 1][2]), "+v"(w2[r + 1][3]),
                          "+v"(w2[r + 2][0]), "+v"(w2[r + 2][1]), "+v"(w2[r + 2][2]), "+v"(w2[r + 2][3]),
                          "+v"(w2[r + 3][0]), "+v"(w2[r + 3][1]), "+v"(w2[r + 3][2]), "+v"(w2[r + 3][3]));
    }

    const int pb0 = c & 1, pb1 = (c >> 1) & 1, pb2 = (c >> 2) & 1;
    const int rl = 4 * pb2 + 2 * pb0 + pb1;   // local row owned after reduce
    const bool upd = (c < 8);                 // one owner lane per (rg, rl)
    const int myrow = 8 * rg + rl;

    const float alpha = 1.f / (1.f + __expf(-sigmas[myrow & 3]));

    if (tid < 12 * 32) hbuf[0][tid] = 0.0f;   // zero incl. padding

    // 4-deep u prefetch pipeline (static register rotation via x4 unroll)
    const size_t ustride = (size_t)BB * HH;
    const float* up = u + (size_t)b * HH + myrow;   // -> u[t=0]
    float uq0 = 0.f, uq1 = 0.f, uq2 = 0.f, uq3 = 0.f;
    if (upd) {
        uq0 = up[0];
        uq1 = up[ustride];
        uq2 = up[2 * ustride];
        uq3 = up[3 * ustride];
    }
    up += 4 * ustride;                               // -> u[t=4]
    float* hp = hist + (size_t)b * HH + myrow;       // -> hist[t=0]
    float hreg = 0.f;                                // h[myrow] (owner lanes)

    __syncthreads();

#define K2_BODY(T, UQ)                                                       \
    {                                                                        \
        const int cur = (T) & 1;                                             \
        float unew = 0.f;                                                    \
        if (upd && (T) + 4 < SS) unew = *up;   /* issue early, wait late */  \
        up += ustride;                                                       \
        const float4 hv0 = *(const float4*)&hbuf[cur][12 * c];               \
        const float4 hv1 = *(const float4*)&hbuf[cur][12 * c + 4];           \
        const v2f hA = (v2f){hv0.x, hv0.y};                                  \
        const v2f hB = (v2f){hv0.z, hv0.w};                                  \
        const v2f hC = (v2f){hv1.x, hv1.y};                                  \
        const v2f hD = (v2f){hv1.z, hv1.w};                                  \
        float s[8];                                                          \
        _Pragma("unroll")                                                    \
        for (int r = 0; r < 8; ++r) {                                        \
            v2f a = w2[r][0] * hA;                                           \
            a += w2[r][1] * hB;                                              \
            a += w2[r][2] * hC;                                              \
            a += w2[r][3] * hD;                                              \
            s[r] = a.x + a.y;                                                \
        }                                                                    \
        /* stage 1: xor7 (row_half_mirror), halve by pb2: keep 4 rows */     \
        float t1[4];                                                         \
        _Pragma("unroll")                                                    \
        for (int i = 0; i < 4; ++i) {                                        \
            const float g = pb2 ? s[i] : s[i + 4];                           \
            const float k = pb2 ? s[i + 4] : s[i];                           \
            t1[i] = k + dpp_mov_f<0x141>(g);                                 \
        }                                                                    \
        /* stage 2: xor1 (quad_perm 1,0,3,2), halve by pb0: keep 2 */        \
        float t2[2];                                                         \
        _Pragma("unroll")                                                    \
        for (int i = 0; i < 2; ++i) {                                        \
            const float g = pb0 ? t1[i] : t1[i + 2];                         \
            const float k = pb0 ? t1[i + 2] : t1[i];                         \
            t2[i] = k + dpp_mov_f<0xB1>(g);                                  \
        }                                                                    \
        /* stage 3: xor2 (quad_perm 2,3,0,1), halve by pb1: keep 1 */        \
        {                                                                    \
            const float g = pb1 ? t2[0] : t2[1];                             \
            const float k = pb1 ? t2[1] : t2[0];                             \
            float sr = k + dpp_mov_f<0x4E>(g);                               \
            /* stage 4: xor8 (row_ror:8) */                                  \
            sr += dpp_mov_f<0x128>(sr);                                      \
            /* stage 5: xor16 (ds_swizzle, 32-lane window) */                \
            sr += __int_as_float(__builtin_amdgcn_ds_swizzle(                \
                      __float_as_int(sr), 0x401F));                          \
            if (upd) {                                                       \
                const float sin_ = sr + (UQ);                                \
                *hp = hreg;                       /* pre-update h -> y[t] */ \
                hreg = hreg + alpha * (ftanh(sin_) - hreg);                  \
                hbuf[cur ^ 1][12 * rg + rl] = hreg;                          \
                (UQ) = unew;                                                 \
            }                                                                \
        }                                                                    \
        hp += ustride;                                                       \
        /* LDS-only drain + barrier: u loads / hist stores stay in flight */ \
        asm volatile("s_waitcnt lgkmcnt(0)\n\ts_barrier" ::: "memory");      \
    }

    for (int t = 0; t < SS; t += 4) {
        K2_BODY(t,     uq0)
        K2_BODY(t + 1, uq1)
        K2_BODY(t + 2, uq2)
        K2_BODY(t + 3, uq3)
    }
#undef K2_BODY
}

// ---------------------------------------------------------------------------
// K3: y[e,o] = bout[o] + sum_k tanh(bhx[k] + sum_i hist[e,i]Whx[i,k]) * Wout[k,o]
// 32 rows/block, 256 threads. Same register-tiling scheme.
// ---------------------------------------------------------------------------
__global__ __launch_bounds__(256) void k3_y(
    const float* __restrict__ hist, const float* __restrict__ Whx,
    const float* __restrict__ bhx, const float* __restrict__ Wout,
    const float* __restrict__ bout, float* __restrict__ y)
{
    __shared__ float hs[32][HH];    // 32KB
    __shared__ float gs[32][DHH];   // 16KB
    const int tid = threadIdx.x;
    const size_t row0 = (size_t)blockIdx.x * 32;

    for (int v = tid; v < 32 * HH; v += 256) {
        int r = v >> 8, i = v & 255;
        hs[r][i] = hist[(row0 + r) * HH + i];
    }
    __syncthreads();

    // stage A: gs = tanh(hs @ Whx + bhx). cols aq+32j; rows 4ru..4ru+3. K=256
    {
        const int aq = tid & 31;
        const int ru = tid >> 5;
        v2f aA[4], aB[4];
        #pragma unroll
        for (int i = 0; i < 4; ++i) { aA[i] = (v2f)0.f; aB[i] = (v2f)0.f; }

        #pragma unroll
        for (int kc = 0; kc < 16; ++kc) {   // KC=16
            v2f wA[16], wB[16];
            #pragma unroll
            for (int k = 0; k < 16; ++k) {
                const float* wp = Whx + (size_t)(kc * 16 + k) * DHH + aq;
                wA[k] = (v2f){wp[0],  wp[32]};
                wB[k] = (v2f){wp[64], wp[96]};
            }
            #pragma unroll
            for (int k4 = 0; k4 < 4; ++k4) {
                float4 hv[4];
                #pragma unroll
                for (int i = 0; i < 4; ++i)
                    hv[i] = *(const float4*)&hs[4 * ru + i][kc * 16 + 4 * k4];
                #pragma unroll
                for (int i = 0; i < 4; ++i) {
                    #pragma unroll
                    for (int e = 0; e < 4; ++e) {
                        const float he = (e == 0) ? hv[i].x : (e == 1) ? hv[i].y
                                       : (e == 2) ? hv[i].z : hv[i].w;
                        const v2f hb = (v2f){he, he};
                        aA[i] += wA[4 * k4 + e] * hb;
                        aB[i] += wB[4 * k4 + e] * hb;
                    }
                }
            }
        }
        const float b0 = bhx[aq], b1 = bhx[aq + 32], b2 = bhx[aq + 64], b3 = bhx[aq + 96];
        #pragma unroll
        for (int i = 0; i < 4; ++i) {
            const int r = 4 * ru + i;
            gs[r][aq]      = ftanh(aA[i].x + b0);
            gs[r][aq + 32] = ftanh(aA[i].y + b1);
            gs[r][aq + 64] = ftanh(aB[i].x + b2);
            gs[r][aq + 96] = ftanh(aB[i].y + b3);
        }
    }
    __syncthreads();

    // stage B: y = gs @ Wout + bout. cols o2, o2+32; rows 4ru..4ru+3. K=128
    {
        const int o2 = tid & 31;
        const int ru = tid >> 5;
        v2f acc[4];
        #pragma unroll
        for (int i = 0; i < 4; ++i) acc[i] = (v2f)0.f;

        #pragma unroll
        for (int kc = 0; kc < 2; ++kc) {    // KC=64
            v2f w[64];
            #pragma unroll
            for (int k = 0; k < 64; ++k) {
                const float* wp = Wout + (size_t)(kc * 64 + k) * XDIM + o2;
                w[k] = (v2f){wp[0], wp[32]};
            }
            #pragma unroll
            for (int k4 = 0; k4 < 16; ++k4) {
                float4 gv[4];
                #pragma unroll
                for (int i = 0; i < 4; ++i)
                    gv[i] = *(const float4*)&gs[4 * ru + i][kc * 64 + 4 * k4];
                #pragma unroll
                for (int i = 0; i < 4; ++i) {
                    #pragma unroll
                    for (int e = 0; e < 4; ++e) {
                        const float ge = (e == 0) ? gv[i].x : (e == 1) ? gv[i].y
                                       : (e == 2) ? gv[i].z : gv[i].w;
                        acc[i] += w[4 * k4 + e] * (v2f){ge, ge};
                    }
                }
            }
        }
        const float b0 = bout[o2], b1 = bout[o2 + 32];
        #pragma unroll
        for (int i = 0; i < 4; ++i) {
            const size_t row = row0 + 4 * ru + i;
            y[row * XDIM + o2]      = acc[i].x + b0;
            y[row * XDIM + o2 + 32] = acc[i].y + b1;
        }
    }
}

extern "C" void kernel_launch(void* const* d_in, const int* in_sizes, int n_in,
                              void* d_out, int out_size, void* d_ws, size_t ws_size,
                              hipStream_t stream) {
    const float* x      = (const float*)d_in[0];
    const float* Wx     = (const float*)d_in[1];
    const float* bx     = (const float*)d_in[2];
    const float* Wih    = (const float*)d_in[3];
    const float* bih    = (const float*)d_in[4];
    const float* Whh    = (const float*)d_in[5];
    const float* bhh    = (const float*)d_in[6];
    const float* Whx    = (const float*)d_in[7];
    const float* bhx    = (const float*)d_in[8];
    const float* Wout   = (const float*)d_in[9];
    const float* bout   = (const float*)d_in[10];
    const float* sigmas = (const float*)d_in[11];
    float* y = (float*)d_out;

    float* u    = (float*)d_ws;                   // S*B*H floats = 128 MB
    float* hist = u + (size_t)SS * BB * HH;       // S*B*H floats = 128 MB

    k1_featu<<<(SS * BB) / 64, 256, 0, stream>>>(x, Wx, bx, Wih, bih, bhh, u);
    k2_rnn<<<BB, 1024, 0, stream>>>(u, Whh, sigmas, hist);
    k3_y<<<(SS * BB) / 32, 256, 0, stream>>>(hist, Whx, bhx, Wout, bout, y);
}